// Round 11
// baseline (858.818 us; speedup 1.0000x reference)
//
#include <hip/hip_runtime.h>
#include <cstdint>
#include <cstddef>

// RWKV-7 Tmix forward, MI355X gfx950 — ROUND 15: scan v7 (2 waves/SIMD) +
// barrier-free prescan/post.
// r14: scan v6 221 µs — 1024 waves / 1024 SIMDs = 1 wave/SIMD, zero TLP, chain
// exposed. v7: 32-way v-split (S[2]/lane) -> 2048 waves = 2/SIMD, packaged as
// 512 blocks x 4 waves SHARING one 20.5-KB LDS staging (halves stage FETCH).
// 32-lane k-reduce: 4 DPP stages within-16 + permlane32_swap for lane^32
// (layout kq=(lane&15)|((lane>>5)<<4) makes the cross stage exactly the
// 32-swap). prescan/post: 256-thr blocks, wave=head, __shfl_xor reductions,
// 0 barriers (was 6/18 per block). GEMMs unchanged (r14 swizzled w256).

#define DI __device__ __forceinline__
static constexpr int T_ = 1024, C_ = 2048, H_ = 32;

typedef __attribute__((ext_vector_type(8))) __bf16 bf16x8;
typedef __attribute__((ext_vector_type(4))) float f32x4;
typedef __attribute__((ext_vector_type(8))) unsigned short us8v;
typedef __attribute__((ext_vector_type(4))) unsigned short us4v;
typedef __attribute__((ext_vector_type(2))) unsigned short us2v;
typedef __attribute__((ext_vector_type(2))) int i32x2;

DI float sig_(float z) { return 1.0f / (1.0f + expf(-z)); }

DI unsigned short f2bf(float f) {           // round-to-nearest-even f32 -> bf16
  union { float f; uint32_t u; } v; v.f = f;
  uint32_t u = v.u;
  return (unsigned short)((u + 0x7FFFu + ((u >> 16) & 1u)) >> 16);
}
DI float bf2f(unsigned short h) {
  union { uint32_t u; float f; } v; v.u = ((uint32_t)h) << 16;
  return v.f;
}

// DPP butterfly adds (within 16-lane rows) + permlane32 cross-swap.
DI float dpp_xor1_add(float x) {
  int r = __builtin_amdgcn_update_dpp(0, __float_as_int(x), 0xB1, 0xF, 0xF, true);
  return x + __int_as_float(r);
}
DI float dpp_xor2_add(float x) {
  int r = __builtin_amdgcn_update_dpp(0, __float_as_int(x), 0x4E, 0xF, 0xF, true);
  return x + __int_as_float(r);
}
DI float dpp_hm_add(float x) {
  int r = __builtin_amdgcn_update_dpp(0, __float_as_int(x), 0x141, 0xF, 0xF, true);
  return x + __int_as_float(r);
}
DI float dpp_mir_add(float x) {
  int r = __builtin_amdgcn_update_dpp(0, __float_as_int(x), 0x140, 0xF, 0xF, true);
  return x + __int_as_float(r);
}
DI float cross32_add(float x) {             // x[lane] + x[lane^32], all lanes
  i32x2 p = __builtin_amdgcn_permlane32_swap(__float_as_int(x), __float_as_int(x),
                                             false, false);
  return __int_as_float(p.x) + __int_as_float(p.y);
}

// async global -> LDS DMA (dest = wave-uniform base + lane*size).
DI void gload16(const float* g, float* l) {
  __builtin_amdgcn_global_load_lds(
      (const __attribute__((address_space(1))) uint32_t*)g,
      (__attribute__((address_space(3))) uint32_t*)l, 16, 0, 0);
}
DI void gload16u(const unsigned short* g, unsigned short* l) {
  __builtin_amdgcn_global_load_lds(
      (const __attribute__((address_space(1))) uint32_t*)g,
      (__attribute__((address_space(3))) uint32_t*)l, 16, 0, 0);
}
DI void gload4(const float* g, float* l) {
  __builtin_amdgcn_global_load_lds(
      (const __attribute__((address_space(1))) uint32_t*)g,
      (__attribute__((address_space(3))) uint32_t*)l, 4, 0, 0);
}

// ---------------- fp32 oracle GEMM (G2: K<=128 LoRA-up jobs) ----------------
struct Job {
  const float* A; const float* W; float* C; const float* bias;
  const float* mixv; const float* x; const float* shift;
  int N, K, ntn, aact, epi, tile_end;
};
struct Jobs { Job j[7]; };

__global__ __launch_bounds__(256) void gemm_oracle(Jobs P) {
  __shared__ float As[64][33];
  __shared__ float Ws[32][65];
  int bx = blockIdx.x, ji = 0;
  while (bx >= P.j[ji].tile_end) ++ji;
  Job J = P.j[ji];
  int tix = bx - (ji ? P.j[ji - 1].tile_end : 0);
  int mt = tix / J.ntn, nt = tix % J.ntn;
  int m0 = mt * 64, n0 = nt * 64;
  int tid = threadIdx.x, tx = tid & 15, ty = tid >> 4;
  float acc[4][4] = {};
  for (int k0 = 0; k0 < J.K; k0 += 32) {
    #pragma unroll
    for (int p = 0; p < 8; ++p) {
      int idx = p * 256 + tid;
      int r = idx >> 5, kc = idx & 31;
      int m = m0 + r, k = k0 + kc;
      float a;
      if (J.mixv) {
        float xv = J.x[(size_t)m * C_ + k];
        int t = m & (T_ - 1);
        float xp = (t == 0) ? J.shift[(size_t)(m >> 10) * C_ + k]
                            : J.x[(size_t)(m - 1) * C_ + k];
        a = xv + (xp - xv) * J.mixv[k];
      } else {
        a = J.A[(size_t)m * J.K + k];
        if (J.aact == 1) a = tanhf(a);
        else if (J.aact == 2) a = sig_(a);
      }
      As[r][kc] = a;
    }
    #pragma unroll
    for (int p = 0; p < 8; ++p) {
      int idx = p * 256 + tid;
      int kr = idx >> 6, nc = idx & 63;
      int n = n0 + nc;
      Ws[kr][nc] = (n < J.N) ? J.W[(size_t)(k0 + kr) * J.N + n] : 0.0f;
    }
    __syncthreads();
    #pragma unroll 4
    for (int kc = 0; kc < 32; ++kc) {
      float av[4], bv[4];
      #pragma unroll
      for (int i = 0; i < 4; ++i) av[i] = As[ty * 4 + i][kc];
      #pragma unroll
      for (int jn = 0; jn < 4; ++jn) bv[jn] = Ws[kc][tx * 4 + jn];
      #pragma unroll
      for (int i = 0; i < 4; ++i)
        #pragma unroll
        for (int jn = 0; jn < 4; ++jn) acc[i][jn] += av[i] * bv[jn];
    }
    __syncthreads();
  }
  #pragma unroll
  for (int i = 0; i < 4; ++i) {
    int rw = m0 + ty * 4 + i;
    #pragma unroll
    for (int jn = 0; jn < 4; ++jn) {
      int col = n0 + tx * 4 + jn;
      if (col < J.N) {
        float v = acc[i][jn];
        if (J.epi == 1) v = sig_(J.bias[col] + v);
        else if (J.epi == 2) v = 0.60653065971263342f * sig_(J.bias[col] + v);
        if (J.epi == 3) ((unsigned short*)J.C)[(size_t)rw * J.N + col] = f2bf(v);
        else            J.C[(size_t)rw * J.N + col] = v;
      }
    }
  }
}

// -------- weight transpose+split: src fp32 [K=2048][N] -> hi/lo bf16 [N][2048] --------
struct TJob { const float* src; unsigned short* dh; unsigned short* dl; int N, ntn, tile_end; };
struct TJobs { TJob j[8]; };

__global__ __launch_bounds__(256) void wtrans(TJobs P) {
  __shared__ float t[64][65];
  int bx = blockIdx.x, ji = 0;
  while (bx >= P.j[ji].tile_end) ++ji;
  TJob J = P.j[ji];
  int tix = bx - (ji ? P.j[ji - 1].tile_end : 0);
  int kt = tix / J.ntn, nt = tix % J.ntn;
  int k0 = kt * 64, n0 = nt * 64;
  int tid = threadIdx.x;
  #pragma unroll
  for (int p = 0; p < 16; ++p) {
    int flat = p * 256 + tid;
    int r = flat >> 6, c = flat & 63;
    int n = n0 + c;
    t[r][c] = (n < J.N) ? J.src[(size_t)(k0 + r) * J.N + n] : 0.0f;
  }
  __syncthreads();
  #pragma unroll
  for (int p = 0; p < 8; ++p) {
    int flat = p * 256 + tid;
    int rr = flat >> 5, cc = (flat & 31) * 2;
    if (n0 + rr < J.N) {
      float w0v = t[cc][rr], w1v = t[cc + 1][rr];
      unsigned short h0 = f2bf(w0v), h1 = f2bf(w1v);
      us2v oh, ol;
      oh.x = h0; oh.y = h1;
      ol.x = f2bf(w0v - bf2f(h0));
      ol.y = f2bf(w1v - bf2f(h1));
      size_t off = (size_t)(n0 + rr) * 2048 + k0 + cc;
      *(us2v*)(J.dh + off) = oh;
      *(us2v*)(J.dl + off) = ol;
    }
  }
}

// ---------- split-bf16 MFMA GEMM, 128x256 tile (r14: B source-slot swizzle) ----------
struct GJob {
  const float* A; const unsigned short* Wh; const unsigned short* Wl; float* C;
  const float* mixv; const float* shift;
  int N, K, ntn, kbeg, kend, atomicC, tile_end;
};
struct GJobs { GJob j[8]; };

__global__ __launch_bounds__(256, 2) void gemm_w256(GJobs P) {
  __shared__ unsigned short Ash[128][40];
  __shared__ unsigned short Asl[128][40];
  __shared__ unsigned short Bsh[256][32];
  __shared__ unsigned short Bsl[256][32];
  int bx = blockIdx.x, ji = 0;
  while (bx >= P.j[ji].tile_end) ++ji;
  GJob J = P.j[ji];
  int tix = bx - (ji ? P.j[ji - 1].tile_end : 0);
  int mt = tix / J.ntn, nt = tix % J.ntn;
  int m0 = mt * 128, n0 = nt * 256;
  int tid = threadIdx.x;
  int lane = tid & 63, wid = tid >> 6;
  int wr = wid >> 1, wc = wid & 1;
  int l15 = lane & 15, lg = lane >> 4;
  f32x4 acc[4][8] = {};

  int sr = tid >> 3, skq = tid & 7;
  float ax[4][4], aq[4][4], amv[4];

  auto loadA = [&](int k0) {
    int kk = k0 + skq * 4;
    if (J.mixv) *(float4*)amv = *(const float4*)(J.mixv + kk);
    #pragma unroll
    for (int p = 0; p < 4; ++p) {
      int m = m0 + p * 32 + sr;
      const float* xp0 = J.A + (size_t)m * J.K + kk;
      *(float4*)ax[p] = *(const float4*)xp0;
      if (J.mixv) {
        const float* pp = ((m & (T_ - 1)) == 0)
            ? (J.shift + (size_t)(m >> 10) * C_ + kk)
            : (xp0 - C_);
        *(float4*)aq[p] = *(const float4*)pp;
      }
    }
  };
  auto writeA = [&]() {
    #pragma unroll
    for (int p = 0; p < 4; ++p) {
      us4v oh, ol;
      #pragma unroll
      for (int q = 0; q < 4; ++q) {
        float va = J.mixv ? (ax[p][q] + (aq[p][q] - ax[p][q]) * amv[q]) : ax[p][q];
        unsigned short hq = f2bf(va);
        oh[q] = hq;
        ol[q] = f2bf(va - bf2f(hq));
      }
      int r = p * 32 + sr;
      *(us4v*)&Ash[r][skq * 4] = oh;
      *(us4v*)&Asl[r][skq * 4] = ol;
    }
  };
  auto stageB = [&](int k0) {
    #pragma unroll
    for (int j = 0; j < 4; ++j) {
      int r0 = wid * 64 + j * 16;
      int rdst = r0 + (lane >> 2);
      int nrow = n0 + rdst;
      if (nrow >= J.N) nrow = J.N - 1;
      int ssrc = (lane & 3) ^ ((rdst >> 1) & 3);
      size_t gofs = (size_t)nrow * J.K + k0 + ssrc * 8;
      gload16u(J.Wh + gofs, &Bsh[r0][0]);
      gload16u(J.Wl + gofs, &Bsl[r0][0]);
    }
  };

  loadA(J.kbeg);
  stageB(J.kbeg);
  writeA();
  asm volatile("s_waitcnt vmcnt(0)" ::: "memory");
  __syncthreads();

  for (int k0 = J.kbeg; k0 < J.kend; k0 += 32) {
    bool more = (k0 + 32 < J.kend);
    if (more) loadA(k0 + 32);
    bf16x8 afh[4], afl[4];
    #pragma unroll
    for (int i = 0; i < 4; ++i) {
      int rr = wr * 64 + i * 16 + l15;
      afh[i] = __builtin_bit_cast(bf16x8, *(const us8v*)&Ash[rr][lg * 8]);
      afl[i] = __builtin_bit_cast(bf16x8, *(const us8v*)&Asl[rr][lg * 8]);
    }
    #pragma unroll
    for (int jn = 0; jn < 8; ++jn) {
      int rb = wc * 128 + jn * 16 + l15;
      int sl = (lg ^ ((rb >> 1) & 3)) * 8;
      bf16x8 bh = __builtin_bit_cast(bf16x8, *(const us8v*)&Bsh[rb][sl]);
      bf16x8 bl = __builtin_bit_cast(bf16x8, *(const us8v*)&Bsl[rb][sl]);
      #pragma unroll
      for (int i = 0; i < 4; ++i) {
        acc[i][jn] = __builtin_amdgcn_mfma_f32_16x16x32_bf16(afh[i], bh, acc[i][jn], 0, 0, 0);
        acc[i][jn] = __builtin_amdgcn_mfma_f32_16x16x32_bf16(afl[i], bh, acc[i][jn], 0, 0, 0);
        acc[i][jn] = __builtin_amdgcn_mfma_f32_16x16x32_bf16(afh[i], bl, acc[i][jn], 0, 0, 0);
      }
    }
    __syncthreads();
    if (more) { stageB(k0 + 32); writeA(); }
    asm volatile("s_waitcnt vmcnt(0)" ::: "memory");
    __syncthreads();
  }

  int orow0 = m0 + wr * 64 + 4 * lg;
  int ocol0 = n0 + wc * 128 + l15;
  #pragma unroll
  for (int i = 0; i < 4; ++i) {
    #pragma unroll
    for (int jn = 0; jn < 8; ++jn) {
      int col = ocol0 + jn * 16;
      if (col < J.N) {
        #pragma unroll
        for (int rr = 0; rr < 4; ++rr) {
          size_t idx = (size_t)(orow0 + i * 16 + rr) * J.N + col;
          float v = acc[i][jn][rr];
          if (J.atomicC) atomicAdd(&J.C[idx], v);
          else           J.C[idx] = v;
        }
      }
    }
  }
}

// ------- prescan v2: 16384 blocks x 256 thr (wave = head); shfl reductions -------
__global__ __launch_bounds__(256) void prescan(
    float* __restrict__ kio, float* __restrict__ vio,
    float* __restrict__ amat_ain, float* __restrict__ vmix_bin,
    const float* __restrict__ vfirst,
    const float* __restrict__ k_k, const float* __restrict__ k_a) {
  int gh = blockIdx.x * 4 + (threadIdx.x >> 6);   // (b,t,h) flat 0..65535
  int lane = threadIdx.x & 63;
  int h = gh & (H_ - 1);
  size_t base = (size_t)gh * 64 + lane;
  int cc = h * 64 + lane;
  float kv = kio[base];
  float kkv = kv * k_k[cc];
  float ss = kkv * kkv;
  ss += __shfl_xor(ss, 1);  ss += __shfl_xor(ss, 2);  ss += __shfl_xor(ss, 4);
  ss += __shfl_xor(ss, 8);  ss += __shfl_xor(ss, 16); ss += __shfl_xor(ss, 32);
  float nrm = fmaxf(sqrtf(ss), 1e-12f);
  float kkn = kkv / nrm;
  float av = amat_ain[base];
  float vmv = vmix_bin[base];
  float vv = vio[base];
  kio[base] = kv * (1.0f + (av - 1.0f) * k_a[cc]);
  vio[base] = vv + (vfirst[base] - vv) * vmv;
  amat_ain[base] = -kkn;
  vmix_bin[base] = kkn * av;
}

// ------- wkv scan v7: 512 blocks x 256 thr (4 waves share staging; 2 waves/SIMD) ----
// Wave w owns v-rows {v0+2w, v0+2w+1}; lane: vl=(lane>>4)&1, kq=(lane&15)|((lane>>5)<<4),
// S[2] per lane. k-reduce: 4 DPP (within 16) + permlane32_swap (lane^32). CH=8 dbuf.
static constexpr int CH = 8;

#define LOADSTEP(BUF, S_, Aa, Ww, Kk, Bb, Rr, Vt)                    \
  {                                                                  \
    *(float2*)&Aa[0] = *(const float2*)&lds[BUF][3][S_][kb];         \
    *(float2*)&Ww[0] = *(const float2*)&lds[BUF][2][S_][kb];         \
    *(float2*)&Kk[0] = *(const float2*)&lds[BUF][1][S_][kb];         \
    *(float2*)&Bb[0] = *(const float2*)&lds[BUF][4][S_][kb];         \
    *(float2*)&Rr[0] = *(const float2*)&lds[BUF][0][S_][kb];         \
    Vt = vtl[BUF][S_][vr];                                           \
  }

#define COMPSTEP(Aa, Ww, Kk, Bb, Rr, Vt, TIDX)                       \
  {                                                                  \
    float pa = fmaf(S1, Aa[1], S0 * Aa[0]);                          \
    pa = dpp_xor1_add(pa); pa = dpp_xor2_add(pa);                    \
    pa = dpp_hm_add(pa);   pa = dpp_mir_add(pa);                     \
    float sa = cross32_add(pa);                                      \
    S0 = fmaf(S0, Ww[0], fmaf(Vt, Kk[0], sa * Bb[0]));               \
    S1 = fmaf(S1, Ww[1], fmaf(Vt, Kk[1], sa * Bb[1]));               \
    float py = fmaf(S1, Rr[1], S0 * Rr[0]);                          \
    py = dpp_xor1_add(py); py = dpp_xor2_add(py);                    \
    py = dpp_hm_add(py);   py = dpp_mir_add(py);                     \
    float y = cross32_add(py);                                       \
    if (kq == 0) obf[bh + (size_t)(TIDX)*2048 + v0 + vr] = f2bf(y);  \
  }

__global__ __launch_bounds__(256) void wkv_scan_v7(
    const float* __restrict__ r, const float* __restrict__ k2,
    const float* __restrict__ w, const float* __restrict__ ain,
    const float* __restrict__ bin, const float* __restrict__ vp,
    const float* __restrict__ sInit, unsigned short* __restrict__ obf) {
  __shared__ float lds[2][5][CH][64];      // 20 KiB
  __shared__ float vtl[2][CH][8];          // 512 B
  int D = blockIdx.x;
  int chain = (D & 7) + 8 * (D >> 6);      // 8 sibling blocks share D&7 -> same XCD
  int vblk = (D >> 3) & 7;
  int b = chain >> 5, h = chain & 31;
  int v0 = vblk * 8;
  int tid = threadIdx.x;
  int wid = tid >> 6, lane = tid & 63;
  int vl = (lane >> 4) & 1;
  int kq = (lane & 15) | ((lane >> 5) << 4);
  int kb = kq * 2;
  int vr = 2 * wid + vl;                   // 0..7 within block
  size_t bh = (size_t)(b * T_) * 2048 + (size_t)h * 64;

  float S0, S1;
  {
    const float* sp = sInit + (((size_t)chain * 64 + v0 + vr) * 64) + kb;
    float2 s = *(const float2*)sp;
    S0 = s.x; S1 = s.y;
  }

  const float* arr[5] = {r, k2, w, ain, bin};

  // 10 main DMAs (array d>>1, t-half d&1) distributed over 4 waves; vt by wave 2.
  auto stage = [&](int buf, int t0) {
    for (int d = wid; d < 10; d += 4) {
      int a = d >> 1, hf = d & 1;
      size_t gofs = bh + (size_t)(t0 + hf * 4 + (lane >> 4)) * 2048 + (lane & 15) * 4;
      gload16(arr[a] + gofs, &lds[buf][a][hf * 4][0]);
    }
    if (wid == 2) {
      size_t gofs = bh + (size_t)(t0 + (lane >> 3)) * 2048 + v0 + (lane & 7);
      gload4(vp + gofs, &vtl[buf][0][0]);
    }
  };

  stage(0, 0);
  asm volatile("s_waitcnt vmcnt(0)" ::: "memory");
  __syncthreads();

  float A0[2], W0[2], K0[2], B0[2], R0[2], vt0;
  float A1[2], W1[2], K1[2], B1[2], R1[2], vt1;

  for (int c = 0; c < T_ / CH; ++c) {
    int cur = c & 1;
    if (c + 1 < T_ / CH) stage(cur ^ 1, (c + 1) * CH);
    int t0 = c * CH;
    LOADSTEP(cur, 0, A0, W0, K0, B0, R0, vt0);
    #pragma unroll 2
    for (int s = 0; s < CH; s += 2) {
      LOADSTEP(cur, s + 1, A1, W1, K1, B1, R1, vt1);
      COMPSTEP(A0, W0, K0, B0, R0, vt0, t0 + s);
      if (s + 2 < CH) LOADSTEP(cur, s + 2, A0, W0, K0, B0, R0, vt0);
      COMPSTEP(A1, W1, K1, B1, R1, vt1, t0 + s + 1);
    }
    asm volatile("s_waitcnt vmcnt(0)" ::: "memory");
    __syncthreads();
  }
}

// ------- post v2: 16384 blocks x 256 thr (wave = head); shfl reductions, 0 barriers ----
__global__ __launch_bounds__(256) void post(
    const unsigned short* __restrict__ obf, const float* __restrict__ r,
    const float* __restrict__ k2, const float* __restrict__ vp,
    const unsigned short* __restrict__ gbf, const float* __restrict__ r_k,
    const float* __restrict__ lnw, const float* __restrict__ lnb,
    float* __restrict__ afin) {
  int gh = blockIdx.x * 4 + (threadIdx.x >> 6);
  int lane = threadIdx.x & 63;
  int h = gh & 31;
  size_t base = (size_t)gh * 64 + lane;
  int cc = h * 64 + lane;
  float ov = bf2f(obf[base]);
  float pr = r[base] * k2[base] * r_k[cc];
  float so = ov, so2 = ov * ov, sd = pr;     // three independent reductions
  #pragma unroll
  for (int d = 1; d <= 32; d <<= 1) {
    so  += __shfl_xor(so, d);
    so2 += __shfl_xor(so2, d);
    sd  += __shfl_xor(sd, d);
  }
  float mu = so * (1.0f / 64.0f);
  float var = so2 * (1.0f / 64.0f) - mu * mu;
  float on = (ov - mu) * rsqrtf(var + 6.4e-4f) * lnw[cc] + lnb[cc];
  float val = (on + sd * vp[base]) * bf2f(gbf[base]);
  afin[base] = val;
}

// ---------------- host ----------------
static constexpr size_t KB = 1024;
static constexpr size_t O_R    = 0;
static constexpr size_t O_K    = 16384;
static constexpr size_t O_V    = 32768;
static constexpr size_t O_WDEC = 49152;
static constexpr size_t O_AMAT = 65536;
static constexpr size_t O_VMIX = 81920;
static constexpr size_t O_AIN  = O_AMAT;
static constexpr size_t O_BIN  = O_VMIX;
static constexpr size_t O_AFIN = O_VMIX;
static constexpr size_t O_WRT_H = 49152, O_WRT_L = 57344;
static constexpr size_t O_WKT_H = 65536, O_WKT_L = 73728;
static constexpr size_t O_WVT_H = 81920, O_WVT_L = 90112;   // ends 98304
static constexpr size_t O_W1T_H = 98304, O_W1T_L = 98560;
static constexpr size_t O_A1T_H = 98816, O_A1T_L = 99072;
static constexpr size_t O_V1T_H = 99328, O_V1T_L = 99456;
static constexpr size_t O_G1T_H = 99584, O_G1T_L = 100096;  // ends 100608
static constexpr size_t O_WOT_H = 0, O_WOT_L = 8192;

extern "C" void kernel_launch(void* const* d_in, const int* in_sizes, int n_in,
                              void* d_out, int out_size, void* d_ws, size_t ws_size,
                              hipStream_t stream) {
  const float* x      = (const float*)d_in[0];
  const float* vfirst = (const float*)d_in[1];
  const float* shift  = (const float*)d_in[2];
  const float* wkv0   = (const float*)d_in[3];
  const float* x_r = (const float*)d_in[4];
  const float* x_w = (const float*)d_in[5];
  const float* x_k = (const float*)d_in[6];
  const float* x_v = (const float*)d_in[7];
  const float* x_a = (const float*)d_in[8];
  const float* x_g = (const float*)d_in[9];
  const float* w0 = (const float*)d_in[10];
  const float* w1 = (const float*)d_in[11];
  const float* w2 = (const float*)d_in[12];
  const float* a0 = (const float*)d_in[13];
  const float* a1 = (const float*)d_in[14];
  const float* a2 = (const float*)d_in[15];
  const float* v0 = (const float*)d_in[16];
  const float* v1 = (const float*)d_in[17];
  const float* v2 = (const float*)d_in[18];
  const float* g1 = (const float*)d_in[19];
  const float* g2 = (const float*)d_in[20];
  const float* k_k = (const float*)d_in[21];
  const float* k_a = (const float*)d_in[22];
  const float* r_k = (const float*)d_in[23];
  const float* W_r = (const float*)d_in[24];
  const float* W_k = (const float*)d_in[25];
  const float* W_v = (const float*)d_in[26];
  const float* W_o = (const float*)d_in[27];
  const float* ln_w = (const float*)d_in[28];
  const float* ln_b = (const float*)d_in[29];

  char* ws = (char*)d_ws;
  auto F = [&](size_t kb) { return (float*)(ws + kb * KB); };
  auto U = [&](size_t kb) { return (unsigned short*)(ws + kb * KB); };
  float* outp = (float*)d_out;
  unsigned short* gbf = (unsigned short*)d_out;                       // 8 MiB
  unsigned short* obf = (unsigned short*)((char*)d_out + 8192 * KB);  // 8 MiB
  float* HW2 = (float*)((char*)d_out + 8192 * KB);                    // 512 KiB
  float* HA2 = (float*)((char*)d_out + 8704 * KB);                    // 512 KiB
  float* HV2 = (float*)((char*)d_out + 9216 * KB);                    // 256 KiB
  float* HG2 = (float*)((char*)d_out + 9472 * KB);                    // 1024 KiB

  // T1: transpose+split ALL seven weights (big + small exact-N).
  {
    TJobs TG{};
    int cum = 0, i = 0;
    auto addT = [&](const float* src, size_t hkb, size_t lkb, int N) {
      int ntn = (N + 63) / 64;
      cum += 32 * ntn;
      TG.j[i++] = TJob{src, U(hkb), U(lkb), N, ntn, cum};
    };
    addT(W_r, O_WRT_H, O_WRT_L, 2048);
    addT(W_k, O_WKT_H, O_WKT_L, 2048);
    addT(W_v, O_WVT_H, O_WVT_L, 2048);
    addT(w1, O_W1T_H, O_W1T_L, 64);
    addT(a1, O_A1T_H, O_A1T_L, 64);
    addT(v1, O_V1T_H, O_V1T_L, 32);
    addT(g1, O_G1T_H, O_G1T_L, 128);
    wtrans<<<dim3(cum), dim3(256), 0, stream>>>(TG);
  }

  // G1 (split MFMA, 128x256 tile): r,k,v + 4 LoRA-downs with fused mixes.
  {
    GJobs G{};
    int cum = 0, i = 0;
    auto add = [&](size_t hkb, size_t lkb, float* Cp, const float* mixv, int N) {
      int ntn = (N + 255) / 256;
      cum += 16 * ntn;
      G.j[i++] = GJob{x, U(hkb), U(lkb), Cp, mixv, shift, N, 2048, ntn, 0, 2048, 0, cum};
    };
    add(O_WRT_H, O_WRT_L, F(O_R), x_r, 2048);
    add(O_WKT_H, O_WKT_L, F(O_K), x_k, 2048);
    add(O_WVT_H, O_WVT_L, F(O_V), x_v, 2048);
    add(O_W1T_H, O_W1T_L, HW2, x_w, 64);
    add(O_A1T_H, O_A1T_L, HA2, x_a, 64);
    add(O_V1T_H, O_V1T_L, HV2, x_v, 32);
    add(O_G1T_H, O_G1T_L, HG2, x_g, 128);
    gemm_w256<<<dim3(cum), dim3(256), 0, stream>>>(G);
  }

  // G2 (fp32 oracle): LoRA-up with fused activations/epilogues. g stored bf16 (epi 3).
  {
    Jobs G{};
    int cum = 0, i = 0;
    auto add = [&](const float* A, const float* W, float* C, const float* bias,
                   int K, int aact, int epi) {
      cum += 32 * 32;
      G.j[i++] = Job{A, W, C, bias, nullptr, nullptr, nullptr, 2048, K, 32, aact, epi, cum};
    };
    add(HW2, w2, F(O_WDEC), w0, 64, 1, 2);
    add(HA2, a2, F(O_AMAT), a0, 64, 0, 1);
    add(HV2, v2, F(O_VMIX), v0, 32, 0, 1);
    add(HG2, g2, (float*)gbf, nullptr, 128, 2, 3);
    gemm_oracle<<<dim3(cum), dim3(256), 0, stream>>>(G);
  }

  // prescan v2: 16384 blocks x 256 threads, wave = head.
  prescan<<<dim3(16384), dim3(256), 0, stream>>>(F(O_K), F(O_V), F(O_AMAT), F(O_VMIX),
                                                 vfirst, k_k, k_a);

  // scan v7: 512 blocks x 256 threads (4 waves share staging); o -> bf16 upper d_out.
  wkv_scan_v7<<<dim3(512), dim3(256), 0, stream>>>(F(O_R), F(O_K), F(O_WDEC), F(O_AIN),
                                                   F(O_BIN), F(O_V), wkv0, obf);

  // post v2: 16384 blocks x 256 threads, wave = head.
  post<<<dim3(16384), dim3(256), 0, stream>>>(obf, F(O_R), F(O_K), F(O_V),
                                              gbf, r_k, ln_w, ln_b, F(O_AFIN));

  // d_out consumed by post -> zero it for G3's split-K atomic accumulation.
  hipMemsetAsync(d_out, 0, (size_t)16384 * KB, stream);

  // T2: W_o transpose+split into dead r region.
  {
    TJobs TO{};
    TO.j[0] = TJob{W_o, U(O_WOT_H), U(O_WOT_L), 2048, 32, 1024};
    wtrans<<<dim3(1024), dim3(256), 0, stream>>>(TO);
  }

  // G3 (split MFMA 128x256, split-K 2, atomic): out = afin @ W_o.
  {
    GJobs G{};
    G.j[0] = GJob{F(O_AFIN), U(O_WOT_H), U(O_WOT_L), outp, nullptr, nullptr,
                  2048, 2048, 8, 0, 1024, 1, 128};
    G.j[1] = GJob{F(O_AFIN), U(O_WOT_H), U(O_WOT_L), outp, nullptr, nullptr,
                  2048, 2048, 8, 1024, 2048, 1, 256};
    gemm_w256<<<dim3(256), dim3(256), 0, stream>>>(G);
  }

  (void)in_sizes; (void)n_in; (void)out_size; (void)ws_size;
}

// Round 12
// 823.348 us; speedup vs baseline: 1.0431x; 1.0431x over previous
//
#include <hip/hip_runtime.h>
#include <cstdint>
#include <cstddef>

// RWKV-7 Tmix forward, MI355X gfx950 — ROUND 16: scan v8 (time-windowed segments).
// r15 lesson: wider k-split (v7) doubles per-row reduce cost — v6's 4-row/16-kq
// layout is the efficiency optimum; its limit is 1 wave/SIMD. v8 keeps v6's
// per-wave layout and splits TIME instead: w <= e^-0.5 per step (softplus-0.5
// guarantee) -> state contribution decays ~0.6^t; a 96-step zero-state warmup
// makes segments independent to ~1e-13. 2 segments x 512 steps; 1024 blocks x
// 128 thr (2 waves share staging, 21 KB LDS) = exactly 4 blocks/CU co-resident,
// 2 waves/SIMD, no tail. Longest block: 608 steps (was 1024 serial).
// GEMMs (r14 swizzled w256), prescan/post v2 unchanged.

#define DI __device__ __forceinline__
static constexpr int T_ = 1024, C_ = 2048, H_ = 32;

typedef __attribute__((ext_vector_type(8))) __bf16 bf16x8;
typedef __attribute__((ext_vector_type(4))) float f32x4;
typedef __attribute__((ext_vector_type(8))) unsigned short us8v;
typedef __attribute__((ext_vector_type(4))) unsigned short us4v;
typedef __attribute__((ext_vector_type(2))) unsigned short us2v;

DI float sig_(float z) { return 1.0f / (1.0f + expf(-z)); }

DI unsigned short f2bf(float f) {           // round-to-nearest-even f32 -> bf16
  union { float f; uint32_t u; } v; v.f = f;
  uint32_t u = v.u;
  return (unsigned short)((u + 0x7FFFu + ((u >> 16) & 1u)) >> 16);
}
DI float bf2f(unsigned short h) {
  union { uint32_t u; float f; } v; v.u = ((uint32_t)h) << 16;
  return v.f;
}

// DPP butterfly adds over 16 k-lanes (kq = lane&15).
DI float dpp_xor1_add(float x) {
  int r = __builtin_amdgcn_update_dpp(0, __float_as_int(x), 0xB1, 0xF, 0xF, true);
  return x + __int_as_float(r);
}
DI float dpp_xor2_add(float x) {
  int r = __builtin_amdgcn_update_dpp(0, __float_as_int(x), 0x4E, 0xF, 0xF, true);
  return x + __int_as_float(r);
}
DI float dpp_hm_add(float x) {
  int r = __builtin_amdgcn_update_dpp(0, __float_as_int(x), 0x141, 0xF, 0xF, true);
  return x + __int_as_float(r);
}
DI float dpp_mir_add(float x) {
  int r = __builtin_amdgcn_update_dpp(0, __float_as_int(x), 0x140, 0xF, 0xF, true);
  return x + __int_as_float(r);
}

// async global -> LDS DMA (dest = wave-uniform base + lane*size).
DI void gload16(const float* g, float* l) {
  __builtin_amdgcn_global_load_lds(
      (const __attribute__((address_space(1))) uint32_t*)g,
      (__attribute__((address_space(3))) uint32_t*)l, 16, 0, 0);
}
DI void gload16u(const unsigned short* g, unsigned short* l) {
  __builtin_amdgcn_global_load_lds(
      (const __attribute__((address_space(1))) uint32_t*)g,
      (__attribute__((address_space(3))) uint32_t*)l, 16, 0, 0);
}
DI void gload4(const float* g, float* l) {
  __builtin_amdgcn_global_load_lds(
      (const __attribute__((address_space(1))) uint32_t*)g,
      (__attribute__((address_space(3))) uint32_t*)l, 4, 0, 0);
}

// ---------------- fp32 oracle GEMM (G2: K<=128 LoRA-up jobs) ----------------
struct Job {
  const float* A; const float* W; float* C; const float* bias;
  const float* mixv; const float* x; const float* shift;
  int N, K, ntn, aact, epi, tile_end;
};
struct Jobs { Job j[7]; };

__global__ __launch_bounds__(256) void gemm_oracle(Jobs P) {
  __shared__ float As[64][33];
  __shared__ float Ws[32][65];
  int bx = blockIdx.x, ji = 0;
  while (bx >= P.j[ji].tile_end) ++ji;
  Job J = P.j[ji];
  int tix = bx - (ji ? P.j[ji - 1].tile_end : 0);
  int mt = tix / J.ntn, nt = tix % J.ntn;
  int m0 = mt * 64, n0 = nt * 64;
  int tid = threadIdx.x, tx = tid & 15, ty = tid >> 4;
  float acc[4][4] = {};
  for (int k0 = 0; k0 < J.K; k0 += 32) {
    #pragma unroll
    for (int p = 0; p < 8; ++p) {
      int idx = p * 256 + tid;
      int r = idx >> 5, kc = idx & 31;
      int m = m0 + r, k = k0 + kc;
      float a;
      if (J.mixv) {
        float xv = J.x[(size_t)m * C_ + k];
        int t = m & (T_ - 1);
        float xp = (t == 0) ? J.shift[(size_t)(m >> 10) * C_ + k]
                            : J.x[(size_t)(m - 1) * C_ + k];
        a = xv + (xp - xv) * J.mixv[k];
      } else {
        a = J.A[(size_t)m * J.K + k];
        if (J.aact == 1) a = tanhf(a);
        else if (J.aact == 2) a = sig_(a);
      }
      As[r][kc] = a;
    }
    #pragma unroll
    for (int p = 0; p < 8; ++p) {
      int idx = p * 256 + tid;
      int kr = idx >> 6, nc = idx & 63;
      int n = n0 + nc;
      Ws[kr][nc] = (n < J.N) ? J.W[(size_t)(k0 + kr) * J.N + n] : 0.0f;
    }
    __syncthreads();
    #pragma unroll 4
    for (int kc = 0; kc < 32; ++kc) {
      float av[4], bv[4];
      #pragma unroll
      for (int i = 0; i < 4; ++i) av[i] = As[ty * 4 + i][kc];
      #pragma unroll
      for (int jn = 0; jn < 4; ++jn) bv[jn] = Ws[kc][tx * 4 + jn];
      #pragma unroll
      for (int i = 0; i < 4; ++i)
        #pragma unroll
        for (int jn = 0; jn < 4; ++jn) acc[i][jn] += av[i] * bv[jn];
    }
    __syncthreads();
  }
  #pragma unroll
  for (int i = 0; i < 4; ++i) {
    int rw = m0 + ty * 4 + i;
    #pragma unroll
    for (int jn = 0; jn < 4; ++jn) {
      int col = n0 + tx * 4 + jn;
      if (col < J.N) {
        float v = acc[i][jn];
        if (J.epi == 1) v = sig_(J.bias[col] + v);
        else if (J.epi == 2) v = 0.60653065971263342f * sig_(J.bias[col] + v);
        if (J.epi == 3) ((unsigned short*)J.C)[(size_t)rw * J.N + col] = f2bf(v);
        else            J.C[(size_t)rw * J.N + col] = v;
      }
    }
  }
}

// -------- weight transpose+split: src fp32 [K=2048][N] -> hi/lo bf16 [N][2048] --------
struct TJob { const float* src; unsigned short* dh; unsigned short* dl; int N, ntn, tile_end; };
struct TJobs { TJob j[8]; };

__global__ __launch_bounds__(256) void wtrans(TJobs P) {
  __shared__ float t[64][65];
  int bx = blockIdx.x, ji = 0;
  while (bx >= P.j[ji].tile_end) ++ji;
  TJob J = P.j[ji];
  int tix = bx - (ji ? P.j[ji - 1].tile_end : 0);
  int kt = tix / J.ntn, nt = tix % J.ntn;
  int k0 = kt * 64, n0 = nt * 64;
  int tid = threadIdx.x;
  #pragma unroll
  for (int p = 0; p < 16; ++p) {
    int flat = p * 256 + tid;
    int r = flat >> 6, c = flat & 63;
    int n = n0 + c;
    t[r][c] = (n < J.N) ? J.src[(size_t)(k0 + r) * J.N + n] : 0.0f;
  }
  __syncthreads();
  #pragma unroll
  for (int p = 0; p < 8; ++p) {
    int flat = p * 256 + tid;
    int rr = flat >> 5, cc = (flat & 31) * 2;
    if (n0 + rr < J.N) {
      float w0v = t[cc][rr], w1v = t[cc + 1][rr];
      unsigned short h0 = f2bf(w0v), h1 = f2bf(w1v);
      us2v oh, ol;
      oh.x = h0; oh.y = h1;
      ol.x = f2bf(w0v - bf2f(h0));
      ol.y = f2bf(w1v - bf2f(h1));
      size_t off = (size_t)(n0 + rr) * 2048 + k0 + cc;
      *(us2v*)(J.dh + off) = oh;
      *(us2v*)(J.dl + off) = ol;
    }
  }
}

// ---------- split-bf16 MFMA GEMM, 128x256 tile (r14: B source-slot swizzle) ----------
struct GJob {
  const float* A; const unsigned short* Wh; const unsigned short* Wl; float* C;
  const float* mixv; const float* shift;
  int N, K, ntn, kbeg, kend, atomicC, tile_end;
};
struct GJobs { GJob j[8]; };

__global__ __launch_bounds__(256, 2) void gemm_w256(GJobs P) {
  __shared__ unsigned short Ash[128][40];
  __shared__ unsigned short Asl[128][40];
  __shared__ unsigned short Bsh[256][32];
  __shared__ unsigned short Bsl[256][32];
  int bx = blockIdx.x, ji = 0;
  while (bx >= P.j[ji].tile_end) ++ji;
  GJob J = P.j[ji];
  int tix = bx - (ji ? P.j[ji - 1].tile_end : 0);
  int mt = tix / J.ntn, nt = tix % J.ntn;
  int m0 = mt * 128, n0 = nt * 256;
  int tid = threadIdx.x;
  int lane = tid & 63, wid = tid >> 6;
  int wr = wid >> 1, wc = wid & 1;
  int l15 = lane & 15, lg = lane >> 4;
  f32x4 acc[4][8] = {};

  int sr = tid >> 3, skq = tid & 7;
  float ax[4][4], aq[4][4], amv[4];

  auto loadA = [&](int k0) {
    int kk = k0 + skq * 4;
    if (J.mixv) *(float4*)amv = *(const float4*)(J.mixv + kk);
    #pragma unroll
    for (int p = 0; p < 4; ++p) {
      int m = m0 + p * 32 + sr;
      const float* xp0 = J.A + (size_t)m * J.K + kk;
      *(float4*)ax[p] = *(const float4*)xp0;
      if (J.mixv) {
        const float* pp = ((m & (T_ - 1)) == 0)
            ? (J.shift + (size_t)(m >> 10) * C_ + kk)
            : (xp0 - C_);
        *(float4*)aq[p] = *(const float4*)pp;
      }
    }
  };
  auto writeA = [&]() {
    #pragma unroll
    for (int p = 0; p < 4; ++p) {
      us4v oh, ol;
      #pragma unroll
      for (int q = 0; q < 4; ++q) {
        float va = J.mixv ? (ax[p][q] + (aq[p][q] - ax[p][q]) * amv[q]) : ax[p][q];
        unsigned short hq = f2bf(va);
        oh[q] = hq;
        ol[q] = f2bf(va - bf2f(hq));
      }
      int r = p * 32 + sr;
      *(us4v*)&Ash[r][skq * 4] = oh;
      *(us4v*)&Asl[r][skq * 4] = ol;
    }
  };
  auto stageB = [&](int k0) {
    #pragma unroll
    for (int j = 0; j < 4; ++j) {
      int r0 = wid * 64 + j * 16;
      int rdst = r0 + (lane >> 2);
      int nrow = n0 + rdst;
      if (nrow >= J.N) nrow = J.N - 1;
      int ssrc = (lane & 3) ^ ((rdst >> 1) & 3);
      size_t gofs = (size_t)nrow * J.K + k0 + ssrc * 8;
      gload16u(J.Wh + gofs, &Bsh[r0][0]);
      gload16u(J.Wl + gofs, &Bsl[r0][0]);
    }
  };

  loadA(J.kbeg);
  stageB(J.kbeg);
  writeA();
  asm volatile("s_waitcnt vmcnt(0)" ::: "memory");
  __syncthreads();

  for (int k0 = J.kbeg; k0 < J.kend; k0 += 32) {
    bool more = (k0 + 32 < J.kend);
    if (more) loadA(k0 + 32);
    bf16x8 afh[4], afl[4];
    #pragma unroll
    for (int i = 0; i < 4; ++i) {
      int rr = wr * 64 + i * 16 + l15;
      afh[i] = __builtin_bit_cast(bf16x8, *(const us8v*)&Ash[rr][lg * 8]);
      afl[i] = __builtin_bit_cast(bf16x8, *(const us8v*)&Asl[rr][lg * 8]);
    }
    #pragma unroll
    for (int jn = 0; jn < 8; ++jn) {
      int rb = wc * 128 + jn * 16 + l15;
      int sl = (lg ^ ((rb >> 1) & 3)) * 8;
      bf16x8 bh = __builtin_bit_cast(bf16x8, *(const us8v*)&Bsh[rb][sl]);
      bf16x8 bl = __builtin_bit_cast(bf16x8, *(const us8v*)&Bsl[rb][sl]);
      #pragma unroll
      for (int i = 0; i < 4; ++i) {
        acc[i][jn] = __builtin_amdgcn_mfma_f32_16x16x32_bf16(afh[i], bh, acc[i][jn], 0, 0, 0);
        acc[i][jn] = __builtin_amdgcn_mfma_f32_16x16x32_bf16(afl[i], bh, acc[i][jn], 0, 0, 0);
        acc[i][jn] = __builtin_amdgcn_mfma_f32_16x16x32_bf16(afh[i], bl, acc[i][jn], 0, 0, 0);
      }
    }
    __syncthreads();
    if (more) { stageB(k0 + 32); writeA(); }
    asm volatile("s_waitcnt vmcnt(0)" ::: "memory");
    __syncthreads();
  }

  int orow0 = m0 + wr * 64 + 4 * lg;
  int ocol0 = n0 + wc * 128 + l15;
  #pragma unroll
  for (int i = 0; i < 4; ++i) {
    #pragma unroll
    for (int jn = 0; jn < 8; ++jn) {
      int col = ocol0 + jn * 16;
      if (col < J.N) {
        #pragma unroll
        for (int rr = 0; rr < 4; ++rr) {
          size_t idx = (size_t)(orow0 + i * 16 + rr) * J.N + col;
          float v = acc[i][jn][rr];
          if (J.atomicC) atomicAdd(&J.C[idx], v);
          else           J.C[idx] = v;
        }
      }
    }
  }
}

// ------- prescan v2: 16384 blocks x 256 thr (wave = head); shfl reductions -------
__global__ __launch_bounds__(256) void prescan(
    float* __restrict__ kio, float* __restrict__ vio,
    float* __restrict__ amat_ain, float* __restrict__ vmix_bin,
    const float* __restrict__ vfirst,
    const float* __restrict__ k_k, const float* __restrict__ k_a) {
  int gh = blockIdx.x * 4 + (threadIdx.x >> 6);
  int lane = threadIdx.x & 63;
  int h = gh & (H_ - 1);
  size_t base = (size_t)gh * 64 + lane;
  int cc = h * 64 + lane;
  float kv = kio[base];
  float kkv = kv * k_k[cc];
  float ss = kkv * kkv;
  ss += __shfl_xor(ss, 1);  ss += __shfl_xor(ss, 2);  ss += __shfl_xor(ss, 4);
  ss += __shfl_xor(ss, 8);  ss += __shfl_xor(ss, 16); ss += __shfl_xor(ss, 32);
  float nrm = fmaxf(sqrtf(ss), 1e-12f);
  float kkn = kkv / nrm;
  float av = amat_ain[base];
  float vmv = vmix_bin[base];
  float vv = vio[base];
  kio[base] = kv * (1.0f + (av - 1.0f) * k_a[cc]);
  vio[base] = vv + (vfirst[base] - vv) * vmv;
  amat_ain[base] = -kkn;
  vmix_bin[base] = kkn * av;
}

// -------- wkv scan v8: time-windowed segments, v6 per-wave layout --------
// 1024 blocks x 128 thr: (chain 64, seg 2, vpair 8); 2 waves/block share staging.
// Wave layout: vl = lane>>4 (4 rows), kq = lane&15, S[4]/lane; vr = wid*4+vl.
// seg 0: t 0..511 from wkv0. seg 1: zero-state warmup t 416..511 (discarded,
// decay <= 0.6065^96 ~ 1e-21), outputs t 512..1023. Exactly 4 blocks/CU
// (21 KB LDS) -> all co-resident, 2 waves/SIMD.
static constexpr int CH = 8;
static constexpr int SEG = 512, WU = 96;

#define LOADSTEP(BUF, S_, Aa, Ww, Kk, Bb, Rr, Vt)                  \
  {                                                                \
    *(float4*)&Aa[0] = *(const float4*)&lds[BUF][3][S_][kb];       \
    *(float4*)&Ww[0] = *(const float4*)&lds[BUF][2][S_][kb];       \
    *(float4*)&Kk[0] = *(const float4*)&lds[BUF][1][S_][kb];       \
    *(float4*)&Bb[0] = *(const float4*)&lds[BUF][4][S_][kb];       \
    *(float4*)&Rr[0] = *(const float4*)&lds[BUF][0][S_][kb];       \
    Vt = vtl[BUF][S_][vr];                                         \
  }

#define COMPSTEP(Aa, Ww, Kk, Bb, Rr, Vt, TIDX)                              \
  {                                                                         \
    float p0 = S[0] * Aa[0], p1 = S[1] * Aa[1];                             \
    p0 = fmaf(S[2], Aa[2], p0);                                             \
    p1 = fmaf(S[3], Aa[3], p1);                                             \
    float sa = p0 + p1;                                                     \
    sa = dpp_xor1_add(sa);                                                  \
    sa = dpp_xor2_add(sa);                                                  \
    sa = dpp_hm_add(sa);                                                    \
    sa = dpp_mir_add(sa);                                                   \
    S[0] = fmaf(S[0], Ww[0], fmaf(Vt, Kk[0], sa * Bb[0]));                  \
    S[1] = fmaf(S[1], Ww[1], fmaf(Vt, Kk[1], sa * Bb[1]));                  \
    S[2] = fmaf(S[2], Ww[2], fmaf(Vt, Kk[2], sa * Bb[2]));                  \
    S[3] = fmaf(S[3], Ww[3], fmaf(Vt, Kk[3], sa * Bb[3]));                  \
    float y0 = S[0] * Rr[0], y1 = S[1] * Rr[1];                             \
    y0 = fmaf(S[2], Rr[2], y0);                                             \
    y1 = fmaf(S[3], Rr[3], y1);                                             \
    float y = y0 + y1;                                                      \
    y = dpp_xor1_add(y);                                                    \
    y = dpp_xor2_add(y);                                                    \
    y = dpp_hm_add(y);                                                      \
    y = dpp_mir_add(y);                                                     \
    if (kq == 0 && (TIDX) >= outfrom)                                       \
      obf[bh + (size_t)(TIDX)*2048 + v0 + vr] = f2bf(y);                    \
  }

__global__ __launch_bounds__(128) void wkv_scan_v8(
    const float* __restrict__ r, const float* __restrict__ k2,
    const float* __restrict__ w, const float* __restrict__ ain,
    const float* __restrict__ bin, const float* __restrict__ vp,
    const float* __restrict__ sInit, unsigned short* __restrict__ obf) {
  __shared__ float lds[2][5][CH][64];      // 20 KiB
  __shared__ float vtl[2][CH][8];          // 512 B
  int D = blockIdx.x;
  int chain = (D & 7) + 8 * (D >> 7);      // a chain's 16 blocks share D&7 -> one XCD
  int inner = (D >> 3) & 15;
  int seg = inner >> 3, vpair = inner & 7;
  int b = chain >> 5, h = chain & 31;
  int v0 = vpair * 8;
  int tid = threadIdx.x;
  int wid = tid >> 6, lane = tid & 63;
  int vl = lane >> 4, kq = lane & 15;
  int kb = kq * 4;
  int vr = wid * 4 + vl;                   // 0..7 within block
  size_t bh = (size_t)(b * T_) * 2048 + (size_t)h * 64;

  float S[4];
  if (seg == 0) {
    const float* sp = sInit + (((size_t)chain * 64 + v0 + vr) * 64) + kb;
    float4 s0 = *(const float4*)sp;
    S[0] = s0.x; S[1] = s0.y; S[2] = s0.z; S[3] = s0.w;
  } else {
    S[0] = S[1] = S[2] = S[3] = 0.0f;      // warmed up over WU steps
  }

  const float* arr[5] = {r, k2, w, ain, bin};

  // 10 main DMAs (array d>>1, t-half d&1) split across the 2 waves; vt by wave 0.
  auto stage = [&](int buf, int t0) {
    for (int d = wid; d < 10; d += 2) {
      int a = d >> 1, hf = d & 1;
      size_t gofs = bh + (size_t)(t0 + hf * 4 + (lane >> 4)) * 2048 + (lane & 15) * 4;
      gload16(arr[a] + gofs, &lds[buf][a][hf * 4][0]);
    }
    if (wid == 0) {                        // vt: 8 steps x 8 vrows = 64 lanes x 4B
      size_t gofs = bh + (size_t)(t0 + (lane >> 3)) * 2048 + v0 + (lane & 7);
      gload4(vp + gofs, &vtl[buf][0][0]);
    }
  };

  int tstart = seg ? (SEG - WU) : 0;       // 416 or 0
  int nch = (seg ? (SEG + WU) : SEG) / CH; // 76 or 64
  int outfrom = seg * SEG;

  stage(0, tstart);
  asm volatile("s_waitcnt vmcnt(0)" ::: "memory");
  __syncthreads();

  float A0[4], W0[4], K0[4], B0[4], R0[4], vt0;
  float A1[4], W1[4], K1[4], B1[4], R1[4], vt1;

  for (int c = 0; c < nch; ++c) {
    int cur = c & 1;
    int t0 = tstart + c * CH;
    if (c + 1 < nch) stage(cur ^ 1, t0 + CH);
    LOADSTEP(cur, 0, A0, W0, K0, B0, R0, vt0);
    #pragma unroll 2
    for (int s = 0; s < CH; s += 2) {
      LOADSTEP(cur, s + 1, A1, W1, K1, B1, R1, vt1);
      COMPSTEP(A0, W0, K0, B0, R0, vt0, t0 + s);
      if (s + 2 < CH) LOADSTEP(cur, s + 2, A0, W0, K0, B0, R0, vt0);
      COMPSTEP(A1, W1, K1, B1, R1, vt1, t0 + s + 1);
    }
    asm volatile("s_waitcnt vmcnt(0)" ::: "memory");
    __syncthreads();
  }
}

// ------- post v2: 16384 blocks x 256 thr (wave = head); shfl reductions, 0 barriers ----
__global__ __launch_bounds__(256) void post(
    const unsigned short* __restrict__ obf, const float* __restrict__ r,
    const float* __restrict__ k2, const float* __restrict__ vp,
    const unsigned short* __restrict__ gbf, const float* __restrict__ r_k,
    const float* __restrict__ lnw, const float* __restrict__ lnb,
    float* __restrict__ afin) {
  int gh = blockIdx.x * 4 + (threadIdx.x >> 6);
  int lane = threadIdx.x & 63;
  int h = gh & 31;
  size_t base = (size_t)gh * 64 + lane;
  int cc = h * 64 + lane;
  float ov = bf2f(obf[base]);
  float pr = r[base] * k2[base] * r_k[cc];
  float so = ov, so2 = ov * ov, sd = pr;
  #pragma unroll
  for (int d = 1; d <= 32; d <<= 1) {
    so  += __shfl_xor(so, d);
    so2 += __shfl_xor(so2, d);
    sd  += __shfl_xor(sd, d);
  }
  float mu = so * (1.0f / 64.0f);
  float var = so2 * (1.0f / 64.0f) - mu * mu;
  float on = (ov - mu) * rsqrtf(var + 6.4e-4f) * lnw[cc] + lnb[cc];
  float val = (on + sd * vp[base]) * bf2f(gbf[base]);
  afin[base] = val;
}

// ---------------- host ----------------
static constexpr size_t KB = 1024;
static constexpr size_t O_R    = 0;
static constexpr size_t O_K    = 16384;
static constexpr size_t O_V    = 32768;
static constexpr size_t O_WDEC = 49152;
static constexpr size_t O_AMAT = 65536;
static constexpr size_t O_VMIX = 81920;
static constexpr size_t O_AIN  = O_AMAT;
static constexpr size_t O_BIN  = O_VMIX;
static constexpr size_t O_AFIN = O_VMIX;
static constexpr size_t O_WRT_H = 49152, O_WRT_L = 57344;
static constexpr size_t O_WKT_H = 65536, O_WKT_L = 73728;
static constexpr size_t O_WVT_H = 81920, O_WVT_L = 90112;   // ends 98304
static constexpr size_t O_W1T_H = 98304, O_W1T_L = 98560;
static constexpr size_t O_A1T_H = 98816, O_A1T_L = 99072;
static constexpr size_t O_V1T_H = 99328, O_V1T_L = 99456;
static constexpr size_t O_G1T_H = 99584, O_G1T_L = 100096;  // ends 100608
static constexpr size_t O_WOT_H = 0, O_WOT_L = 8192;

extern "C" void kernel_launch(void* const* d_in, const int* in_sizes, int n_in,
                              void* d_out, int out_size, void* d_ws, size_t ws_size,
                              hipStream_t stream) {
  const float* x      = (const float*)d_in[0];
  const float* vfirst = (const float*)d_in[1];
  const float* shift  = (const float*)d_in[2];
  const float* wkv0   = (const float*)d_in[3];
  const float* x_r = (const float*)d_in[4];
  const float* x_w = (const float*)d_in[5];
  const float* x_k = (const float*)d_in[6];
  const float* x_v = (const float*)d_in[7];
  const float* x_a = (const float*)d_in[8];
  const float* x_g = (const float*)d_in[9];
  const float* w0 = (const float*)d_in[10];
  const float* w1 = (const float*)d_in[11];
  const float* w2 = (const float*)d_in[12];
  const float* a0 = (const float*)d_in[13];
  const float* a1 = (const float*)d_in[14];
  const float* a2 = (const float*)d_in[15];
  const float* v0 = (const float*)d_in[16];
  const float* v1 = (const float*)d_in[17];
  const float* v2 = (const float*)d_in[18];
  const float* g1 = (const float*)d_in[19];
  const float* g2 = (const float*)d_in[20];
  const float* k_k = (const float*)d_in[21];
  const float* k_a = (const float*)d_in[22];
  const float* r_k = (const float*)d_in[23];
  const float* W_r = (const float*)d_in[24];
  const float* W_k = (const float*)d_in[25];
  const float* W_v = (const float*)d_in[26];
  const float* W_o = (const float*)d_in[27];
  const float* ln_w = (const float*)d_in[28];
  const float* ln_b = (const float*)d_in[29];

  char* ws = (char*)d_ws;
  auto F = [&](size_t kb) { return (float*)(ws + kb * KB); };
  auto U = [&](size_t kb) { return (unsigned short*)(ws + kb * KB); };
  float* outp = (float*)d_out;
  unsigned short* gbf = (unsigned short*)d_out;                       // 8 MiB
  unsigned short* obf = (unsigned short*)((char*)d_out + 8192 * KB);  // 8 MiB
  float* HW2 = (float*)((char*)d_out + 8192 * KB);                    // 512 KiB
  float* HA2 = (float*)((char*)d_out + 8704 * KB);                    // 512 KiB
  float* HV2 = (float*)((char*)d_out + 9216 * KB);                    // 256 KiB
  float* HG2 = (float*)((char*)d_out + 9472 * KB);                    // 1024 KiB

  // T1: transpose+split ALL seven weights (big + small exact-N).
  {
    TJobs TG{};
    int cum = 0, i = 0;
    auto addT = [&](const float* src, size_t hkb, size_t lkb, int N) {
      int ntn = (N + 63) / 64;
      cum += 32 * ntn;
      TG.j[i++] = TJob{src, U(hkb), U(lkb), N, ntn, cum};
    };
    addT(W_r, O_WRT_H, O_WRT_L, 2048);
    addT(W_k, O_WKT_H, O_WKT_L, 2048);
    addT(W_v, O_WVT_H, O_WVT_L, 2048);
    addT(w1, O_W1T_H, O_W1T_L, 64);
    addT(a1, O_A1T_H, O_A1T_L, 64);
    addT(v1, O_V1T_H, O_V1T_L, 32);
    addT(g1, O_G1T_H, O_G1T_L, 128);
    wtrans<<<dim3(cum), dim3(256), 0, stream>>>(TG);
  }

  // G1 (split MFMA, 128x256 tile): r,k,v + 4 LoRA-downs with fused mixes.
  {
    GJobs G{};
    int cum = 0, i = 0;
    auto add = [&](size_t hkb, size_t lkb, float* Cp, const float* mixv, int N) {
      int ntn = (N + 255) / 256;
      cum += 16 * ntn;
      G.j[i++] = GJob{x, U(hkb), U(lkb), Cp, mixv, shift, N, 2048, ntn, 0, 2048, 0, cum};
    };
    add(O_WRT_H, O_WRT_L, F(O_R), x_r, 2048);
    add(O_WKT_H, O_WKT_L, F(O_K), x_k, 2048);
    add(O_WVT_H, O_WVT_L, F(O_V), x_v, 2048);
    add(O_W1T_H, O_W1T_L, HW2, x_w, 64);
    add(O_A1T_H, O_A1T_L, HA2, x_a, 64);
    add(O_V1T_H, O_V1T_L, HV2, x_v, 32);
    add(O_G1T_H, O_G1T_L, HG2, x_g, 128);
    gemm_w256<<<dim3(cum), dim3(256), 0, stream>>>(G);
  }

  // G2 (fp32 oracle): LoRA-up with fused activations/epilogues. g stored bf16 (epi 3).
  {
    Jobs G{};
    int cum = 0, i = 0;
    auto add = [&](const float* A, const float* W, float* C, const float* bias,
                   int K, int aact, int epi) {
      cum += 32 * 32;
      G.j[i++] = Job{A, W, C, bias, nullptr, nullptr, nullptr, 2048, K, 32, aact, epi, cum};
    };
    add(HW2, w2, F(O_WDEC), w0, 64, 1, 2);
    add(HA2, a2, F(O_AMAT), a0, 64, 0, 1);
    add(HV2, v2, F(O_VMIX), v0, 32, 0, 1);
    add(HG2, g2, (float*)gbf, nullptr, 128, 2, 3);
    gemm_oracle<<<dim3(cum), dim3(256), 0, stream>>>(G);
  }

  // prescan v2: 16384 blocks x 256 threads, wave = head.
  prescan<<<dim3(16384), dim3(256), 0, stream>>>(F(O_K), F(O_V), F(O_AMAT), F(O_VMIX),
                                                 vfirst, k_k, k_a);

  // scan v8: 1024 blocks x 128 threads (2 segments, 96-step warmup).
  wkv_scan_v8<<<dim3(1024), dim3(128), 0, stream>>>(F(O_R), F(O_K), F(O_WDEC), F(O_AIN),
                                                    F(O_BIN), F(O_V), wkv0, obf);

  // post v2: 16384 blocks x 256 threads, wave = head.
  post<<<dim3(16384), dim3(256), 0, stream>>>(obf, F(O_R), F(O_K), F(O_V),
                                              gbf, r_k, ln_w, ln_b, F(O_AFIN));

  // d_out consumed by post -> zero it for G3's split-K atomic accumulation.
  hipMemsetAsync(d_out, 0, (size_t)16384 * KB, stream);

  // T2: W_o transpose+split into dead r region.
  {
    TJobs TO{};
    TO.j[0] = TJob{W_o, U(O_WOT_H), U(O_WOT_L), 2048, 32, 1024};
    wtrans<<<dim3(1024), dim3(256), 0, stream>>>(TO);
  }

  // G3 (split MFMA 128x256, split-K 2, atomic): out = afin @ W_o.
  {
    GJobs G{};
    G.j[0] = GJob{F(O_AFIN), U(O_WOT_H), U(O_WOT_L), outp, nullptr, nullptr,
                  2048, 2048, 8, 0, 1024, 1, 128};
    G.j[1] = GJob{F(O_AFIN), U(O_WOT_H), U(O_WOT_L), outp, nullptr, nullptr,
                  2048, 2048, 8, 1024, 2048, 1, 256};
    gemm_w256<<<dim3(256), dim3(256), 0, stream>>>(G);
  }

  (void)in_sizes; (void)n_in; (void)out_size; (void)ws_size;
}